// Round 1
// baseline (1290.724 us; speedup 1.0000x reference)
//
#include <hip/hip_runtime.h>

// ---------------------------------------------------------------------------
// Gemma sliding-window attention block on MI355X (gfx950).
// B=2 S=2048 H=2048 NH=16 NKV=8 D=128 INTER=8192 WINDOW=1024
// GEMMs: 256-wide-tile 8-wave deep pipeline (m201/T3+T4 schedule, 4-deep LDS
// ring, counted vmcnt -- never drained to 0 in the main loop), XOR-swizzled
// LDS, XCD-aware block swizzle, setprio around MFMA clusters.
// ---------------------------------------------------------------------------

typedef unsigned short u16;
typedef __attribute__((ext_vector_type(4))) float f32x4;
typedef __attribute__((ext_vector_type(8))) short bf16x8; // 8 bf16 in 4 VGPRs

#define HSZ   2048
#define NH    16
#define NKV   8
#define HD    128
#define INTER 8192
#define SEQ   2048
#define BATCH 2
#define MTOK  (BATCH*SEQ)   // 4096
#define WIN   1024

__device__ __forceinline__ u16 f2bf(float f) {
    union { float f; unsigned int u; } c; c.f = f;
    unsigned int u = c.u;
    u += 0x7fffu + ((u >> 16) & 1u);          // RNE
    return (u16)(u >> 16);
}
__device__ __forceinline__ float bf2f(u16 v) {
    union { unsigned int u; float f; } c; c.u = ((unsigned int)v) << 16;
    return c.f;
}
__device__ __forceinline__ float sq4(float4 v) {
    return v.x*v.x + v.y*v.y + v.z*v.z + v.w*v.w;
}
__device__ __forceinline__ void async_ld16(const void* g, void* l) {
    __builtin_amdgcn_global_load_lds(
        (const __attribute__((address_space(1))) void*)g,
        (__attribute__((address_space(3))) void*)l, 16, 0, 0);
}
// erf via Abramowitz-Stegun 7.1.26, |eps| <= 1.5e-7 (vs bf16 storage 4e-3)
__device__ __forceinline__ float fast_erf(float x) {
    float ax = fabsf(x);
    float t = 1.0f / (1.0f + 0.3275911f * ax);
    float y = t * (0.254829592f + t * (-0.284496736f + t * (1.421413741f +
              t * (-1.453152027f + t * 1.061405429f))));
    float e = 1.0f - y * __expf(-x * x);
    return copysignf(e, x);
}

// ---------------------------------------------------------------------------
// Weight conversion
// ---------------------------------------------------------------------------
__global__ __launch_bounds__(256) void cvt_f32_bf16_k(const float* __restrict__ src,
                                                      u16* __restrict__ dst, int n4) {
    int i = blockIdx.x * 256 + threadIdx.x;
    if (i >= n4) return;
    float4 v = ((const float4*)src)[i];
    ushort4 o;
    o.x = f2bf(v.x); o.y = f2bf(v.y); o.z = f2bf(v.z); o.w = f2bf(v.w);
    ((ushort4*)dst)[i] = o;
}

// Interleave gate/up rows: dst row 2j = w_gate[j], row 2j+1 = w_up[j]
__global__ __launch_bounds__(256) void cvt_gu_k(const float* __restrict__ wg,
                                                const float* __restrict__ wu,
                                                u16* __restrict__ dst) {
    long i4 = ((long)blockIdx.x * 256 + threadIdx.x) * 4;
    int r = (int)(i4 >> 11);
    int c = (int)(i4 & 2047);
    const float* srow = ((r & 1) ? wu : wg) + (long)(r >> 1) * HSZ + c;
    float4 v = *(const float4*)srow;
    ushort4 o;
    o.x = f2bf(v.x); o.y = f2bf(v.y); o.z = f2bf(v.z); o.w = f2bf(v.w);
    *(ushort4*)(dst + i4) = o;
}

// ---------------------------------------------------------------------------
// RMSNorm f32 x -> bf16
// ---------------------------------------------------------------------------
__global__ __launch_bounds__(256) void rmsnorm_bf16_k(const float* __restrict__ x,
                                                      const float* __restrict__ w,
                                                      u16* __restrict__ out) {
    const int row = blockIdx.x, t = threadIdx.x;
    __shared__ float sb[4];
    const float4* xr = (const float4*)(x + (long)row * HSZ);
    float4 v0 = xr[t], v1 = xr[t + 256];
    float ss = sq4(v0) + sq4(v1);
#pragma unroll
    for (int o = 32; o; o >>= 1) ss += __shfl_xor(ss, o);
    if ((t & 63) == 0) sb[t >> 6] = ss;
    __syncthreads();
    ss = sb[0] + sb[1] + sb[2] + sb[3];
    const float rs = rsqrtf(ss * (1.f / HSZ) + 1e-6f);
    const float4* wr = (const float4*)w;
    float4 w0 = wr[t], w1 = wr[t + 256];
    ushort4 o0, o1;
    o0.x = f2bf(v0.x * rs * w0.x); o0.y = f2bf(v0.y * rs * w0.y);
    o0.z = f2bf(v0.z * rs * w0.z); o0.w = f2bf(v0.w * rs * w0.w);
    o1.x = f2bf(v1.x * rs * w1.x); o1.y = f2bf(v1.y * rs * w1.y);
    o1.z = f2bf(v1.z * rs * w1.z); o1.w = f2bf(v1.w * rs * w1.w);
    ushort4* orow = (ushort4*)(out + (long)row * HSZ);
    orow[t] = o0; orow[t + 256] = o1;
}

// ---------------------------------------------------------------------------
// GEMM: C[M,N] = A[M,K](bf16) @ Bw[N,K]^T(bf16).
// Deep-pipelined template (m201-style, T3+T4+T5+T1):
//   - tile BM=256 x BN=NF*64, BK=32, 512 threads = 8 waves (2M x 4N),
//     per-wave output 128 x NF*16 (NF=4 -> 128x64, 42.7 FLOP/LDS-byte).
//   - LDS: ring of FOUR K-tile buffers (A 4x16KB + B 4x(NF*4)KB).
//     Stage K-tile t+3 during tile t's phases -> writes hit buffer (t-1)&3,
//     whose reads finished before tile t's first barrier: NO timing races.
//   - vmcnt(2*LPT) once per K-tile (tiles t+2,t+3 in flight), never 0 in the
//     main loop; peeled tail tiles use vmcnt(LPT)/vmcnt(0).
//   - 2 phases per K-tile (mh = which 64-row half of the wave's 128 rows),
//     16 (NF=4) MFMAs per phase wrapped in s_setprio(1/0); raw s_barrier
//     with sched_barrier(0) pinning the phase skeleton.
//   - LDS swizzle: 64B rows, 16B chunk' = chunk ^ ((row>>1)&3) (involution);
//     staged via pre-swizzled GLOBAL source + linear global_load_lds dest,
//     read with the same XOR -> conflict-free ds_read_b128 (verified 0 in
//     the previous kernel's counters with this exact scheme).
//   - XCD swizzle: linear block id remapped (orig%8)*(nwg/8)+orig/8
//     (all grids have nwg%8==0 -> bijective).
// EPI 1: bf16 out.  EPI 2: gelu(gate)*up -> bf16, N/2 cols (interleaved Bw).
// ---------------------------------------------------------------------------

#define VM_WAIT(n) asm volatile("s_waitcnt vmcnt(" #n ")" ::: "memory")

// stage A-tile of K-tile kt_ into ring buffer pb_ (2 x 8KB rounds)
#define STAGE_A(pb_, kt_) { \
    const u16* s_ = Ag + (long)(kt_) * 32; \
    u16* d_ = (u16*)As + (pb_) * ATILE + (wave << 9); \
    async_ld16(s_, d_); \
    async_ld16(s_ + (long)128 * K, d_ + 4096); }

// stage B-tile (2 rounds for NF=4, 1 round for NF=2)
#define STAGE_B(pb_, kt_) { \
    const u16* s_ = Bg + (long)(kt_) * 32; \
    u16* d_ = (u16*)Bs + (pb_) * BTILE + (wave << 9); \
    async_ld16(s_, d_); \
    if constexpr (NF == 4) { async_ld16(s_ + (long)128 * K, d_ + 4096); } }

// one K-tile = 2 phases. VMW_ runs at end of phase 1, before the barrier that
// releases the next tile's ds_reads (each wave waits its OWN stages; barrier
// then makes that a group guarantee).
#define KTILE(t_, DOSTAGE_, VMW_) { \
    const int buf_ = (t_) & 3; \
    const u16* Ab_ = (const u16*)As + buf_ * ATILE; \
    const u16* Bb_ = (const u16*)Bs + buf_ * BTILE; \
    const int pf_ = (t_) + 3; \
    const int pb_ = pf_ & 3; \
    bf16x8 af[4]; \
    /* ---- phase 0: rows wm*128 .. +63 ---- */ \
    _Pragma("unroll") \
    for (int mi = 0; mi < 4; ++mi) \
        af[mi] = *(const bf16x8*)(Ab_ + aoff + mi * 512); \
    _Pragma("unroll") \
    for (int ni = 0; ni < NF; ++ni) \
        bfr[ni] = *(const bf16x8*)(Bb_ + boff + ni * 512); \
    if (DOSTAGE_) { STAGE_A(pb_, pf_); } \
    __builtin_amdgcn_sched_barrier(0); \
    __builtin_amdgcn_s_barrier(); \
    __builtin_amdgcn_s_setprio(1); \
    _Pragma("unroll") \
    for (int mi = 0; mi < 4; ++mi) \
        _Pragma("unroll") \
        for (int ni = 0; ni < NF; ++ni) \
            acc[mi][ni] = __builtin_amdgcn_mfma_f32_16x16x32_bf16( \
                af[mi], bfr[ni], acc[mi][ni], 0, 0, 0); \
    __builtin_amdgcn_s_setprio(0); \
    __builtin_amdgcn_sched_barrier(0); \
    __builtin_amdgcn_s_barrier(); \
    /* ---- phase 1: rows wm*128+64 .. +127 (B frags reused) ---- */ \
    _Pragma("unroll") \
    for (int mi = 0; mi < 4; ++mi) \
        af[mi] = *(const bf16x8*)(Ab_ + aoff + 2048 + mi * 512); \
    if (DOSTAGE_) { STAGE_B(pb_, pf_); } \
    VMW_; \
    __builtin_amdgcn_sched_barrier(0); \
    __builtin_amdgcn_s_barrier(); \
    __builtin_amdgcn_s_setprio(1); \
    _Pragma("unroll") \
    for (int mi = 0; mi < 4; ++mi) \
        _Pragma("unroll") \
        for (int ni = 0; ni < NF; ++ni) \
            acc[4 + mi][ni] = __builtin_amdgcn_mfma_f32_16x16x32_bf16( \
                af[mi], bfr[ni], acc[4 + mi][ni], 0, 0, 0); \
    __builtin_amdgcn_s_setprio(0); \
    __builtin_amdgcn_sched_barrier(0); \
    __builtin_amdgcn_s_barrier(); \
}

template <int NF, int EPI>
__global__ __launch_bounds__(512, 2) void gemm_pipe(const u16* __restrict__ A,
                                                    const u16* __restrict__ Bw,
                                                    u16* __restrict__ outp,
                                                    int N, int K) {
    constexpr int BN    = NF * 64;
    constexpr int ATILE = 256 * 32;        // u16 elems (16 KB)
    constexpr int BTILE = BN * 32;         // 16 KB (NF=4) / 8 KB (NF=2)
    __shared__ alignas(16) u16 As[4 * ATILE];      // 64 KB
    __shared__ alignas(16) u16 Bs[4 * BTILE];      // 64 / 32 KB

    const int tid  = threadIdx.x;
    const int wave = tid >> 6;              // 0..7
    const int lane = tid & 63;
    const int wm   = wave >> 2;             // 0..1 -> rows wm*128..+127
    const int wn   = wave & 3;              // 0..3 -> cols wn*(NF*16)..

    // XCD-aware bijective block swizzle (all launches: nwg % 8 == 0)
    const int nwg  = gridDim.x * gridDim.y;
    const int orig = blockIdx.y * gridDim.x + blockIdx.x;
    const int swz  = (orig & 7) * (nwg >> 3) + (orig >> 3);
    const int m0   = (swz % gridDim.x) << 8;         // gridDim.x = M/256 = 16
    const int n0   = (swz / gridDim.x) * BN;

    const int lrow = lane & 15;
    // swizzled within-row chunk position for ds_read (constant per lane:
    // row = 16k + lrow  ->  (row>>1)&3 == (lrow>>1)&3)
    const int px   = (((lane >> 4) ^ ((lrow >> 1) & 3)) << 3);
    const int aoff = ((wm << 7) + lrow) * 32 + px;
    const int boff = (wn * (NF * 16) + lrow) * 32 + px;

    // staging source (global pre-swizzled so linear global_load_lds dest +
    // swizzled ds_read agree): thread covers LDS row tid>>2, chunk tid&3.
    const int srow = tid >> 2;                       // 0..127 per round
    const int scol = (((tid & 3) ^ ((tid >> 3) & 3)) << 3);
    const u16* Ag = A  + (long)(m0 + srow) * K + scol;
    const u16* Bg = Bw + (long)(n0 + srow) * K + scol;

    f32x4 acc[8][NF] = {};
    bf16x8 bfr[NF];

    const int NT = K >> 5;                 // K-tiles of 32 (>= 64 here)
    constexpr int LPT = (NF == 4) ? 4 : 3; // global_load_lds per wave per tile

    // prologue: stage tiles 0,1,2; wait own tile-0 loads; barrier = everyone's
    STAGE_A(0, 0); STAGE_B(0, 0);
    STAGE_A(1, 1); STAGE_B(1, 1);
    STAGE_A(2, 2); STAGE_B(2, 2);
    if constexpr (NF == 4) { VM_WAIT(8); } else { VM_WAIT(6); }
    __builtin_amdgcn_s_barrier();

    // main loop: stage t+3, compute t; allow tiles t+2,t+3 (= 2*LPT) in flight
    for (int t = 0; t < NT - 3; ++t) {
        if constexpr (NF == 4) { KTILE(t, 1, VM_WAIT(8)); }
        else                   { KTILE(t, 1, VM_WAIT(6)); }
    }
    // peeled tail: no staging; shrink the allowance so remaining tiles land
    if constexpr (NF == 4) { KTILE((NT - 3), 0, VM_WAIT(4)); }
    else                   { KTILE((NT - 3), 0, VM_WAIT(3)); }
    KTILE((NT - 2), 0, VM_WAIT(0));
    KTILE((NT - 1), 0, ((void)0));

    // ---- epilogue (C/D: col = lane&15, row = (lane>>4)*4 + r) ----
    const int drow = (lane >> 4) << 2;
    if constexpr (EPI == 1) {
#pragma unroll
        for (int mi8 = 0; mi8 < 8; ++mi8) {
            const int rb = m0 + (wm << 7) + ((mi8 >> 2) << 6) + ((mi8 & 3) << 4) + drow;
#pragma unroll
            for (int ni = 0; ni < NF; ++ni) {
                const int col = n0 + wn * (NF * 16) + ni * 16 + lrow;
#pragma unroll
                for (int r = 0; r < 4; ++r)
                    outp[(long)(rb + r) * N + col] = f2bf(acc[mi8][ni][r]);
            }
        }
    } else {
        // paired GELU epilogue: even lanes own tile ni, odd lanes tile ni+1;
        // every lane computes exactly one erf per output value.
        const int No = N >> 1;
#pragma unroll
        for (int mi8 = 0; mi8 < 8; ++mi8) {
            const int rb = m0 + (wm << 7) + ((mi8 >> 2) << 6) + ((mi8 & 3) << 4) + drow;
#pragma unroll
            for (int ni = 0; ni < NF; ni += 2) {
                const int colown = n0 + wn * 64 + (ni + (lane & 1)) * 16 + lrow;
#pragma unroll
                for (int r = 0; r < 4; ++r) {
                    float a = acc[mi8][ni][r];
                    float b = acc[mi8][ni + 1][r];
                    float a1 = __shfl_xor(a, 1);
                    float b1 = __shfl_xor(b, 1);
                    float g = (lane & 1) ? b1 : a;
                    float u = (lane & 1) ? b  : a1;
                    float act = 0.5f * g * (1.f + fast_erf(g * 0.70710678f)) * u;
                    outp[(long)(rb + r) * No + (colown >> 1)] = f2bf(act);
                }
            }
        }
    }
}

// ---------------------------------------------------------------------------
// RoPE + repack qkv(bf16 [M][4096]) -> Qh [B][NH][S][HD], Kh [B][NKV][S][HD]
// ---------------------------------------------------------------------------
__global__ __launch_bounds__(128) void rope_repack_k(const u16* __restrict__ qkv,
                                                     u16* __restrict__ Qh,
                                                     u16* __restrict__ Kh) {
    const int m = blockIdx.x;       // token 0..4095
    const int slot = blockIdx.y;    // 0..15 q head, 16..23 kv head
    const int d = threadIdx.x;      // 0..127
    const int b = m >> 11, s = m & 2047;
    const int colbase = (slot < 16) ? (slot << 7) : (2048 + ((slot - 16) << 7));
    const float xv = bf2f(qkv[(long)m * 4096 + colbase + d]);
    const float xp = bf2f(qkv[(long)m * 4096 + colbase + (d ^ 64)]);
    const int i = d & 63;
    // 10000^(-2i/128) = exp2(-i * log2(10000)/64)
    const float inv = exp2f(-(float)i * 0.20762050593045864f);
    const float fr = (float)s * inv;
    const float cs = cosf(fr), sn = sinf(fr);
    const float ov = (d < 64) ? (xv * cs - xp * sn) : (xv * cs + xp * sn);
    if (slot < 16) {
        Qh[(((long)(b * NH + slot)) * SEQ + s) * HD + d] = f2bf(ov);
    } else {
        Kh[(((long)(b * NKV + (slot - 16))) * SEQ + s) * HD + d] = f2bf(ov);
    }
}

// V transpose: qkv[m][3072+g*128+d] -> Vt [B][NKV][HD][S]
__global__ __launch_bounds__(256) void v_transpose_k(const u16* __restrict__ qkv,
                                                     u16* __restrict__ Vt) {
    __shared__ alignas(16) u16 tile[64][130];
    const int st = blockIdx.x, g = blockIdx.y, b = blockIdx.z;
    const int s0 = st * 64;
    const int tid = threadIdx.x;
#pragma unroll
    for (int i = 0; i < 32; ++i) {
        int idx = i * 256 + tid;
        int sl = idx >> 7, d = idx & 127;
        tile[sl][d] = qkv[(long)(b * SEQ + s0 + sl) * 4096 + 3072 + g * 128 + d];
    }
    __syncthreads();
#pragma unroll
    for (int i = 0; i < 32; ++i) {
        int idx = i * 256 + tid;
        int d = idx >> 6, sl = idx & 63;
        Vt[((long)(b * NKV + g) * HD + d) * SEQ + s0 + sl] = tile[sl][d];
    }
}

// ---------------------------------------------------------------------------
// Flash attention. 4 waves/block, Q-tile 64 (wave owns 16 q rows), K-tile 64.
// ---------------------------------------------------------------------------
__global__ __launch_bounds__(256) void flash_attn_k(const u16* __restrict__ Qh,
                                                    const u16* __restrict__ Kh,
                                                    const u16* __restrict__ Vt,
                                                    u16* __restrict__ attn) {
    __shared__ alignas(16) u16 Qs[64 * 128];
    __shared__ alignas(16) u16 Ks[64 * 128];
    __shared__ alignas(16) u16 Vts[128 * 64];
    __shared__ alignas(16) u16 Ps[4][16 * 64];
    const int tid = threadIdx.x;
    const int wave = tid >> 6, lane = tid & 63;
    const int qt = blockIdx.x, h = blockIdx.y, b = blockIdx.z;
    const int g = h >> 1;                    // GQA group of 2
    const int q0 = qt * 64;
    const u16* Qg = Qh + (((long)(b * NH + h) * SEQ) + q0) * HD;
    const u16* Kg = Kh + ((long)(b * NKV + g) * SEQ) * HD;
    const u16* Vg = Vt + ((long)(b * NKV + g) * HD) * SEQ;

    {   // stage Q tile (contiguous 16KB)
        const int4* src = (const int4*)Qg;
        int4* dst = (int4*)Qs;
#pragma unroll
        for (int i = 0; i < 4; ++i) dst[tid + i * 256] = src[tid + i * 256];
    }
    __syncthreads();
    const int lrow = lane & 15;
    const int kq = (lane >> 4) << 3;
    bf16x8 aq[4];
#pragma unroll
    for (int ks = 0; ks < 4; ++ks)
        aq[ks] = *(const bf16x8*)(Qs + (wave * 16 + lrow) * 128 + ks * 32 + kq);

    f32x4 o[8] = {};
    float mrow[4], lsum[4];
#pragma unroll
    for (int r = 0; r < 4; ++r) { mrow[r] = -1e30f; lsum[r] = 0.f; }

    const int jlo = (q0 - (WIN - 1)) > 0 ? (q0 - (WIN - 1)) : 0;
    const int t0 = jlo >> 6, t1 = q0 >> 6;
    for (int jt = t0; jt <= t1; ++jt) {
        const int j0 = jt * 64;
        __syncthreads();   // prior tile's LDS reads done
        {   // stage K tile
            const int4* src = (const int4*)(Kg + (long)j0 * HD);
            int4* dst = (int4*)Ks;
#pragma unroll
            for (int i = 0; i < 4; ++i) dst[tid + i * 256] = src[tid + i * 256];
        }
        {   // stage Vt tile: 128 rows x 64 cols
            const int row = tid >> 1, half = tid & 1;
            const int4* src = (const int4*)(Vg + (long)row * SEQ + j0 + half * 32);
            int4* dst = (int4*)(Vts + row * 64 + half * 32);
#pragma unroll
            for (int i = 0; i < 4; ++i) dst[i] = src[i];
        }
        __syncthreads();

        // ---- scores: 16x64 per wave
        f32x4 sc[4];
#pragma unroll
        for (int nt = 0; nt < 4; ++nt) {
            f32x4 s = {};
#pragma unroll
            for (int ks = 0; ks < 4; ++ks) {
                bf16x8 bk = *(const bf16x8*)(Ks + (nt * 16 + lrow) * 128 + ks * 32 + kq);
                s = __builtin_amdgcn_mfma_f32_16x16x32_bf16(aq[ks], bk, s, 0, 0, 0);
            }
            sc[nt] = s;
        }

        // ---- mask + online softmax
        const int qbase = q0 + wave * 16 + ((lane >> 4) << 2);
        float pv[4][4];   // [nt][r]
#pragma unroll
        for (int r = 0; r < 4; ++r) {
            const int qi = qbase + r;
            float mx = -1e30f;
#pragma unroll
            for (int nt = 0; nt < 4; ++nt) {
                const int ki = j0 + nt * 16 + lrow;
                float s = sc[nt][r] * 0.08838834764831845f;  // 1/sqrt(128)
                bool valid = (ki <= qi) && (qi - ki < WIN);
                s = valid ? s : -1e30f;
                sc[nt][r] = s;
                mx = fmaxf(mx, s);
            }
            mx = fmaxf(mx, __shfl_xor(mx, 1));
            mx = fmaxf(mx, __shfl_xor(mx, 2));
            mx = fmaxf(mx, __shfl_xor(mx, 4));
            mx = fmaxf(mx, __shfl_xor(mx, 8));
            const float mn = fmaxf(mrow[r], mx);
            const float alpha = __expf(mrow[r] - mn);
            float rsum = 0.f;
#pragma unroll
            for (int nt = 0; nt < 4; ++nt) {
                float s = sc[nt][r];
                float p = (s > -1e29f) ? __expf(s - mn) : 0.f;
                pv[nt][r] = p;
                rsum += p;
            }
            rsum += __shfl_xor(rsum, 1);
            rsum += __shfl_xor(rsum, 2);
            rsum += __shfl_xor(rsum, 4);
            rsum += __shfl_xor(rsum, 8);
            lsum[r] = lsum[r] * alpha + rsum;
            mrow[r] = mn;
#pragma unroll
            for (int dt = 0; dt < 8; ++dt) o[dt][r] *= alpha;
        }

        // ---- P: C-layout -> LDS (per-wave region, A-layout for PV)
        u16* myP = (u16*)Ps[wave];
#pragma unroll
        for (int r = 0; r < 4; ++r) {
            const int prow = ((lane >> 4) << 2) + r;
#pragma unroll
            for (int nt = 0; nt < 4; ++nt)
                myP[prow * 64 + nt * 16 + lrow] = f2bf(pv[nt][r]);
        }
        __syncthreads();

        // ---- PV: O[16][128] += P[16][64] @ V[64][128]
#pragma unroll
        for (int kst = 0; kst < 2; ++kst) {
            bf16x8 ap = *(const bf16x8*)(myP + lrow * 64 + kst * 32 + kq);
#pragma unroll
            for (int dt = 0; dt < 8; ++dt) {
                bf16x8 bv = *(const bf16x8*)(Vts + (dt * 16 + lrow) * 64 + kst * 32 + kq);
                o[dt] = __builtin_amdgcn_mfma_f32_16x16x32_bf16(ap, bv, o[dt], 0, 0, 0);
            }
        }
    }

    // ---- epilogue
#pragma unroll
    for (int r = 0; r < 4; ++r) {
        const int qi = q0 + wave * 16 + ((lane >> 4) << 2) + r;
        const float inv = 1.f / lsum[r];
        const long mrowg = (long)b * SEQ + qi;
#pragma unroll
        for (int dt = 0; dt < 8; ++dt)
            attn[mrowg * (NH * HD) + h * 128 + dt * 16 + lrow] = f2bf(o[dt][r] * inv);
    }
}

// ---------------------------------------------------------------------------
// h2 = x + rmsnorm(attn_out)*w_post (bf16) ; ffin = bf16(rmsnorm(h2)*w_pre)
// ---------------------------------------------------------------------------
__global__ __launch_bounds__(256) void addnorm2_k(const float* __restrict__ x,
                                                  const u16* __restrict__ ao,
                                                  const float* __restrict__ wpost,
                                                  const float* __restrict__ wpre,
                                                  u16* __restrict__ h2,
                                                  u16* __restrict__ ffin) {
    const int row = blockIdx.x, t = threadIdx.x;
    __shared__ float sb[4];
    const long base = (long)row * HSZ;
    ushort4 a4_0 = ((const ushort4*)(ao + base))[t];
    ushort4 a4_1 = ((const ushort4*)(ao + base))[t + 256];
    float4 a0, a1;
    a0.x = bf2f(a4_0.x); a0.y = bf2f(a4_0.y); a0.z = bf2f(a4_0.z); a0.w = bf2f(a4_0.w);
    a1.x = bf2f(a4_1.x); a1.y = bf2f(a4_1.y); a1.z = bf2f(a4_1.z); a1.w = bf2f(a4_1.w);
    float ss = sq4(a0) + sq4(a1);
#pragma unroll
    for (int o = 32; o; o >>= 1) ss += __shfl_xor(ss, o);
    if ((t & 63) == 0) sb[t >> 6] = ss;
    __syncthreads();
    ss = sb[0] + sb[1] + sb[2] + sb[3];
    const float rs1 = rsqrtf(ss * (1.f / HSZ) + 1e-6f);

    const float4* xr = (const float4*)(x + base);
    float4 x0 = xr[t], x1 = xr[t + 256];
    float4 wp0 = ((const float4*)wpost)[t], wp1 = ((const float4*)wpost)[t + 256];
    float4 h0, h1;
    h0.x = x0.x + a0.x * rs1 * wp0.x; h0.y = x0.y + a0.y * rs1 * wp0.y;
    h0.z = x0.z + a0.z * rs1 * wp0.z; h0.w = x0.w + a0.w * rs1 * wp0.w;
    h1.x = x1.x + a1.x * rs1 * wp1.x; h1.y = x1.y + a1.y * rs1 * wp1.y;
    h1.z = x1.z + a1.z * rs1 * wp1.z; h1.w = x1.w + a1.w * rs1 * wp1.w;
    ushort4 hb0, hb1;
    hb0.x = f2bf(h0.x); hb0.y = f2bf(h0.y); hb0.z = f2bf(h0.z); hb0.w = f2bf(h0.w);
    hb1.x = f2bf(h1.x); hb1.y = f2bf(h1.y); hb1.z = f2bf(h1.z); hb1.w = f2bf(h1.w);
    ((ushort4*)(h2 + base))[t] = hb0;
    ((ushort4*)(h2 + base))[t + 256] = hb1;

    float ss2 = sq4(h0) + sq4(h1);
#pragma unroll
    for (int o = 32; o; o >>= 1) ss2 += __shfl_xor(ss2, o);
    __syncthreads();   // all sb reads above done
    if ((t & 63) == 0) sb[t >> 6] = ss2;
    __syncthreads();
    ss2 = sb[0] + sb[1] + sb[2] + sb[3];
    const float rs2 = rsqrtf(ss2 * (1.f / HSZ) + 1e-6f);
    float4 wq0 = ((const float4*)wpre)[t], wq1 = ((const float4*)wpre)[t + 256];
    ushort4 o0, o1;
    o0.x = f2bf(h0.x * rs2 * wq0.x); o0.y = f2bf(h0.y * rs2 * wq0.y);
    o0.z = f2bf(h0.z * rs2 * wq0.z); o0.w = f2bf(h0.w * rs2 * wq0.w);
    o1.x = f2bf(h1.x * rs2 * wq1.x); o1.y = f2bf(h1.y * rs2 * wq1.y);
    o1.z = f2bf(h1.z * rs2 * wq1.z); o1.w = f2bf(h1.w * rs2 * wq1.w);
    ushort4* fr = (ushort4*)(ffin + base);
    fr[t] = o0; fr[t + 256] = o1;
}

// out = (h2 + rmsnorm(ffn_out)*w_post_ffn) * layer_scalar   (f32 out)
__global__ __launch_bounds__(256) void final_k(const u16* __restrict__ h2,
                                               const u16* __restrict__ fo,
                                               const float* __restrict__ wpost,
                                               const float* __restrict__ lscal,
                                               float* __restrict__ out) {
    const int row = blockIdx.x, t = threadIdx.x;
    __shared__ float sb[4];
    const long base = (long)row * HSZ;
    ushort4 f4_0 = ((const ushort4*)(fo + base))[t];
    ushort4 f4_1 = ((const ushort4*)(fo + base))[t + 256];
    float4 f0, f1;
    f0.x = bf2f(f4_0.x); f0.y = bf2f(f4_0.y); f0.z = bf2f(f4_0.z); f0.w = bf2f(f4_0.w);
    f1.x = bf2f(f4_1.x); f1.y = bf2f(f4_1.y); f1.z = bf2f(f4_1.z); f1.w = bf2f(f4_1.w);
    float ss = sq4(f0) + sq4(f1);
#pragma unroll
    for (int o = 32; o; o >>= 1) ss += __shfl_xor(ss, o);
    if ((t & 63) == 0) sb[t >> 6] = ss;
    __syncthreads();
    ss = sb[0] + sb[1] + sb[2] + sb[3];
    const float rs = rsqrtf(ss * (1.f / HSZ) + 1e-6f);
    const float sc = lscal[0];
    ushort4 h4_0 = ((const ushort4*)(h2 + base))[t];
    ushort4 h4_1 = ((const ushort4*)(h2 + base))[t + 256];
    float4 wp0 = ((const float4*)wpost)[t], wp1 = ((const float4*)wpost)[t + 256];
    float4 r0, r1;
    r0.x = (bf2f(h4_0.x) + f0.x * rs * wp0.x) * sc;
    r0.y = (bf2f(h4_0.y) + f0.y * rs * wp0.y) * sc;
    r0.z = (bf2f(h4_0.z) + f0.z * rs * wp0.z) * sc;
    r0.w = (bf2f(h4_0.w) + f0.w * rs * wp0.w) * sc;
    r1.x = (bf2f(h4_1.x) + f1.x * rs * wp1.x) * sc;
    r1.y = (bf2f(h4_1.y) + f1.y * rs * wp1.y) * sc;
    r1.z = (bf2f(h4_1.z) + f1.z * rs * wp1.z) * sc;
    r1.w = (bf2f(h4_1.w) + f1.w * rs * wp1.w) * sc;
    ((float4*)(out + base))[t] = r0;
    ((float4*)(out + base))[t + 256] = r1;
}

// ---------------------------------------------------------------------------
extern "C" void kernel_launch(void* const* d_in, const int* in_sizes, int n_in,
                              void* d_out, int out_size, void* d_ws, size_t ws_size,
                              hipStream_t stream) {
    (void)in_sizes; (void)n_in; (void)out_size;
    const float* x     = (const float*)d_in[0];
    const float* wq    = (const float*)d_in[1];
    const float* wk    = (const float*)d_in[2];
    const float* wv    = (const float*)d_in[3];
    const float* wo    = (const float*)d_in[4];
    const float* w_in  = (const float*)d_in[5];
    const float* w_pa  = (const float*)d_in[6];
    const float* w_pf  = (const float*)d_in[7];
    const float* w_pff = (const float*)d_in[8];
    const float* wgate = (const float*)d_in[9];
    const float* wup   = (const float*)d_in[10];
    const float* wdown = (const float*)d_in[11];
    const float* lscal = (const float*)d_in[12];
    float* out = (float*)d_out;

    // -------- workspace layout: 264 MiB total, phase-overlapped ----------
    const size_t NEED = 276824064ull;  // 264 MiB
    if (ws_size < NEED) return;
    char* ws = (char*)d_ws;
    u16* Wqkv  = (u16*)(ws);                             // 16 MB  [whole run]
    u16* Wo    = (u16*)(ws + 16777216);                  //  8 MB
    u16* Wgu   = (u16*)(ws + 25165824);                  // 64 MB
    u16* Wdown = (u16*)(ws + 92274688);                  // 32 MB
    u16* act   = (u16*)(ws + 125829120);                 // 64 MB  [gate-up out]
    u16* R1    = (u16*)(ws + 192937984);                 // 32 MB
    u16* R2    = (u16*)(ws + 226492416);                 // 32 MB
    u16* R3    = (u16*)(ws + 260046848);                 // 16 MB
    u16* qkvb = R1;
    u16* aout = R1;
    u16* ffin = R1 + 8388608;
    u16* fout = R1 + 8388608;
    u16* Qh = R2;
    u16* Kh = R2 + 8388608;
    u16* Vt = R2 + 12582912;
    u16* h2 = R2;
    u16* hnorm = R3;
    u16* attn  = R3;

    // weight conversions (re-run every launch; ws is re-poisoned)
    cvt_f32_bf16_k<<<4096, 256, 0, stream>>>(wq, Wqkv, 2048 * 2048 / 4);
    cvt_f32_bf16_k<<<2048, 256, 0, stream>>>(wk, Wqkv + 2048 * 2048, 1024 * 2048 / 4);
    cvt_f32_bf16_k<<<2048, 256, 0, stream>>>(wv, Wqkv + 3072 * 2048, 1024 * 2048 / 4);
    cvt_f32_bf16_k<<<4096, 256, 0, stream>>>(wo, Wo, 2048 * 2048 / 4);
    cvt_gu_k<<<32768, 256, 0, stream>>>(wgate, wup, Wgu);
    cvt_f32_bf16_k<<<16384, 256, 0, stream>>>(wdown, Wdown, HSZ * INTER / 4);

    // block pipeline. GEMM grids: dim3(M/256, N/BN); all have nwg % 8 == 0.
    rmsnorm_bf16_k<<<MTOK, 256, 0, stream>>>(x, w_in, hnorm);
    gemm_pipe<4, 1><<<dim3(16, 16), 512, 0, stream>>>(hnorm, Wqkv, qkvb, 4096, HSZ);
    rope_repack_k<<<dim3(MTOK, 24), 128, 0, stream>>>(qkvb, Qh, Kh);
    v_transpose_k<<<dim3(SEQ / 64, NKV, BATCH), 256, 0, stream>>>(qkvb, Vt);
    flash_attn_k<<<dim3(SEQ / 64, NH, BATCH), 256, 0, stream>>>(Qh, Kh, Vt, attn);
    gemm_pipe<2, 1><<<dim3(16, 16), 512, 0, stream>>>(attn, Wo, aout, HSZ, HSZ);
    addnorm2_k<<<MTOK, 256, 0, stream>>>(x, aout, w_pa, w_pf, h2, ffin);
    gemm_pipe<4, 2><<<dim3(16, 64), 512, 0, stream>>>(ffin, Wgu, act, 2 * INTER, HSZ);
    gemm_pipe<2, 1><<<dim3(16, 16), 512, 0, stream>>>(act, Wdown, fout, HSZ, INTER);
    final_k<<<MTOK, 256, 0, stream>>>(h2, fout, w_pff, lscal, out);
}

// Round 2
// 1045.693 us; speedup vs baseline: 1.2343x; 1.2343x over previous
//
#include <hip/hip_runtime.h>

// ---------------------------------------------------------------------------
// Gemma sliding-window attention block on MI355X (gfx950).
// B=2 S=2048 H=2048 NH=16 NKV=8 D=128 INTER=8192 WINDOW=1024
// GEMMs: 256-wide-tile 8-wave deep pipeline. Round-2 fix: LDS->reg fragment
// loads are INLINE-ASM ds_read_b128 so the compiler's waitcnt pass cannot
// insert hidden vmcnt(0) drains against the outstanding global_load_lds
// prefetches (that killed round 1). Manual lgkmcnt(0)+sched_barrier per
// rule #18. Counted vmcnt never reaches 0 in the main loop.
// ---------------------------------------------------------------------------

typedef unsigned short u16;
typedef __attribute__((ext_vector_type(4))) float f32x4;
typedef __attribute__((ext_vector_type(8))) short bf16x8; // 8 bf16 in 4 VGPRs

#define HSZ   2048
#define NH    16
#define NKV   8
#define HD    128
#define INTER 8192
#define SEQ   2048
#define BATCH 2
#define MTOK  (BATCH*SEQ)   // 4096
#define WIN   1024

__device__ __forceinline__ u16 f2bf(float f) {
    union { float f; unsigned int u; } c; c.f = f;
    unsigned int u = c.u;
    u += 0x7fffu + ((u >> 16) & 1u);          // RNE
    return (u16)(u >> 16);
}
__device__ __forceinline__ float bf2f(u16 v) {
    union { unsigned int u; float f; } c; c.u = ((unsigned int)v) << 16;
    return c.f;
}
__device__ __forceinline__ float sq4(float4 v) {
    return v.x*v.x + v.y*v.y + v.z*v.z + v.w*v.w;
}
__device__ __forceinline__ void async_ld16(const void* g, void* l) {
    __builtin_amdgcn_global_load_lds(
        (const __attribute__((address_space(1))) void*)g,
        (__attribute__((address_space(3))) void*)l, 16, 0, 0);
}
// LDS byte address (32-bit) of a generic pointer into a __shared__ array
__device__ __forceinline__ unsigned lds_addr(const void* p) {
    return (unsigned)(unsigned long long)(const __attribute__((address_space(3))) void*)p;
}
// inline-asm ds_read_b128: invisible to the waitcnt pass -> no hidden
// vmcnt(0) against outstanding global_load_lds. OFF is a compile-time imm.
template <int OFF>
__device__ __forceinline__ bf16x8 ds_read128(unsigned a) {
    bf16x8 r;
    asm volatile("ds_read_b128 %0, %1 offset:%2" : "=v"(r) : "v"(a), "n"(OFF));
    return r;
}
// erf via Abramowitz-Stegun 7.1.26, |eps| <= 1.5e-7 (vs bf16 storage 4e-3)
__device__ __forceinline__ float fast_erf(float x) {
    float ax = fabsf(x);
    float t = 1.0f / (1.0f + 0.3275911f * ax);
    float y = t * (0.254829592f + t * (-0.284496736f + t * (1.421413741f +
              t * (-1.453152027f + t * 1.061405429f))));
    float e = 1.0f - y * __expf(-x * x);
    return copysignf(e, x);
}

// ---------------------------------------------------------------------------
// Weight conversion
// ---------------------------------------------------------------------------
__global__ __launch_bounds__(256) void cvt_f32_bf16_k(const float* __restrict__ src,
                                                      u16* __restrict__ dst, int n4) {
    int i = blockIdx.x * 256 + threadIdx.x;
    if (i >= n4) return;
    float4 v = ((const float4*)src)[i];
    ushort4 o;
    o.x = f2bf(v.x); o.y = f2bf(v.y); o.z = f2bf(v.z); o.w = f2bf(v.w);
    ((ushort4*)dst)[i] = o;
}

// Interleave gate/up rows: dst row 2j = w_gate[j], row 2j+1 = w_up[j]
__global__ __launch_bounds__(256) void cvt_gu_k(const float* __restrict__ wg,
                                                const float* __restrict__ wu,
                                                u16* __restrict__ dst) {
    long i4 = ((long)blockIdx.x * 256 + threadIdx.x) * 4;
    int r = (int)(i4 >> 11);
    int c = (int)(i4 & 2047);
    const float* srow = ((r & 1) ? wu : wg) + (long)(r >> 1) * HSZ + c;
    float4 v = *(const float4*)srow;
    ushort4 o;
    o.x = f2bf(v.x); o.y = f2bf(v.y); o.z = f2bf(v.z); o.w = f2bf(v.w);
    *(ushort4*)(dst + i4) = o;
}

// ---------------------------------------------------------------------------
// RMSNorm f32 x -> bf16
// ---------------------------------------------------------------------------
__global__ __launch_bounds__(256) void rmsnorm_bf16_k(const float* __restrict__ x,
                                                      const float* __restrict__ w,
                                                      u16* __restrict__ out) {
    const int row = blockIdx.x, t = threadIdx.x;
    __shared__ float sb[4];
    const float4* xr = (const float4*)(x + (long)row * HSZ);
    float4 v0 = xr[t], v1 = xr[t + 256];
    float ss = sq4(v0) + sq4(v1);
#pragma unroll
    for (int o = 32; o; o >>= 1) ss += __shfl_xor(ss, o);
    if ((t & 63) == 0) sb[t >> 6] = ss;
    __syncthreads();
    ss = sb[0] + sb[1] + sb[2] + sb[3];
    const float rs = rsqrtf(ss * (1.f / HSZ) + 1e-6f);
    const float4* wr = (const float4*)w;
    float4 w0 = wr[t], w1 = wr[t + 256];
    ushort4 o0, o1;
    o0.x = f2bf(v0.x * rs * w0.x); o0.y = f2bf(v0.y * rs * w0.y);
    o0.z = f2bf(v0.z * rs * w0.z); o0.w = f2bf(v0.w * rs * w0.w);
    o1.x = f2bf(v1.x * rs * w1.x); o1.y = f2bf(v1.y * rs * w1.y);
    o1.z = f2bf(v1.z * rs * w1.z); o1.w = f2bf(v1.w * rs * w1.w);
    ushort4* orow = (ushort4*)(out + (long)row * HSZ);
    orow[t] = o0; orow[t + 256] = o1;
}

// ---------------------------------------------------------------------------
// GEMM: C[M,N] = A[M,K](bf16) @ Bw[N,K]^T(bf16).
// Deep-pipelined template (m201-style, T1-T5):
//   - tile BM=256 x BN=NF*64, BK=32, 512 threads = 8 waves (2M x 4N),
//     per-wave output 128 x NF*16.
//   - LDS ring of FOUR K-tile buffers. Stage K-tile t+3 during tile t's
//     phases -> writes hit buffer (t-1)&3, whose reads completed before a
//     prior barrier: structurally race-free, no timing assumptions.
//   - vmcnt(2*LPT) once per K-tile (keeps tiles t+2,t+3 in flight), NEVER 0
//     in the main loop; peeled tail shrinks the allowance LPT -> 0.
//   - fragment loads are inline-asm ds_read_b128 (waitcnt pass can't see
//     them -> no hidden drains); explicit lgkmcnt(0)+sched_barrier(0) after
//     the pre-MFMA barrier (rule #18); sched_barrier(0) fences pin the
//     phase skeleton; s_setprio(1) around each 16-MFMA cluster.
//   - LDS swizzle: 64B rows, 16B chunk' = chunk ^ ((row>>1)&3) (involution),
//     staged via pre-swizzled GLOBAL source + linear global_load_lds dest,
//     read with the same XOR -> conflict-free ds_read_b128 (measured 0).
//   - XCD swizzle: (orig%8)*(nwg/8)+orig/8 (all grids nwg%8==0 -> bijective).
// EPI 1: bf16 out.  EPI 2: gelu(gate)*up -> bf16, N/2 cols (interleaved Bw).
// ---------------------------------------------------------------------------

#define VM_WAIT(n) asm volatile("s_waitcnt vmcnt(" #n ")" ::: "memory")
#define LGKM0      asm volatile("s_waitcnt lgkmcnt(0)" ::: "memory")
#define SBAR       __builtin_amdgcn_s_barrier()
#define SCHED0     __builtin_amdgcn_sched_barrier(0)

// stage A-tile of K-tile kt_ into ring buffer pb_ (2 x 8KB rounds)
#define STAGE_A(pb_, kt_) { \
    const u16* s_ = Ag + (long)(kt_) * 32; \
    u16* d_ = (u16*)As + (pb_) * ATILE + (wave << 9); \
    async_ld16(s_, d_); \
    async_ld16(s_ + (long)128 * K, d_ + 4096); }

// stage B-tile (2 rounds for NF=4, 1 round for NF=2)
#define STAGE_B(pb_, kt_) { \
    const u16* s_ = Bg + (long)(kt_) * 32; \
    u16* d_ = (u16*)Bs + (pb_) * BTILE + (wave << 9); \
    async_ld16(s_, d_); \
    if constexpr (NF == 4) { async_ld16(s_ + (long)128 * K, d_ + 4096); } }

// one K-tile = 2 phases of 16 (NF=4) MFMAs each.
#define KTILE(t_, DOSTAGE_, VMW_) { \
    const unsigned abuf_ = aAb + (unsigned)(((t_) & 3) * (ATILE * 2)); \
    const unsigned bbuf_ = aBb + (unsigned)(((t_) & 3) * (BTILE * 2)); \
    const int pf_ = (t_) + 3; \
    const int pb_ = pf_ & 3; \
    bf16x8 af[4]; \
    /* ---- phase 0: rows wm*128 .. +63 ---- */ \
    af[0] = ds_read128<0>(abuf_);    af[1] = ds_read128<1024>(abuf_); \
    af[2] = ds_read128<2048>(abuf_); af[3] = ds_read128<3072>(abuf_); \
    bfr[0] = ds_read128<0>(bbuf_);   bfr[1] = ds_read128<1024>(bbuf_); \
    if constexpr (NF == 4) { \
        bfr[2] = ds_read128<2048>(bbuf_); bfr[3] = ds_read128<3072>(bbuf_); } \
    if (DOSTAGE_) { STAGE_A(pb_, pf_); } \
    SCHED0; SBAR; LGKM0; SCHED0; \
    __builtin_amdgcn_s_setprio(1); \
    _Pragma("unroll") \
    for (int mi = 0; mi < 4; ++mi) \
        _Pragma("unroll") \
        for (int ni = 0; ni < NF; ++ni) \
            acc[mi][ni] = __builtin_amdgcn_mfma_f32_16x16x32_bf16( \
                af[mi], bfr[ni], acc[mi][ni], 0, 0, 0); \
    __builtin_amdgcn_s_setprio(0); \
    SCHED0; SBAR; SCHED0; \
    /* ---- phase 1: rows wm*128+64 .. +127 (B frags reused) ---- */ \
    af[0] = ds_read128<4096>(abuf_); af[1] = ds_read128<5120>(abuf_); \
    af[2] = ds_read128<6144>(abuf_); af[3] = ds_read128<7168>(abuf_); \
    if (DOSTAGE_) { STAGE_B(pb_, pf_); } \
    SCHED0; VMW_; \
    SCHED0; SBAR; LGKM0; SCHED0; \
    __builtin_amdgcn_s_setprio(1); \
    _Pragma("unroll") \
    for (int mi = 0; mi < 4; ++mi) \
        _Pragma("unroll") \
        for (int ni = 0; ni < NF; ++ni) \
            acc[4 + mi][ni] = __builtin_amdgcn_mfma_f32_16x16x32_bf16( \
                af[mi], bfr[ni], acc[4 + mi][ni], 0, 0, 0); \
    __builtin_amdgcn_s_setprio(0); \
    SCHED0; SBAR; SCHED0; \
}

template <int NF, int EPI>
__global__ __launch_bounds__(512, 2) void gemm_pipe(const u16* __restrict__ A,
                                                    const u16* __restrict__ Bw,
                                                    u16* __restrict__ outp,
                                                    int N, int K) {
    constexpr int BN    = NF * 64;
    constexpr int ATILE = 256 * 32;        // u16 elems (16 KB)
    constexpr int BTILE = BN * 32;         // 16 KB (NF=4) / 8 KB (NF=2)
    __shared__ alignas(16) u16 As[4 * ATILE];      // 64 KB
    __shared__ alignas(16) u16 Bs[4 * BTILE];      // 64 / 32 KB

    const int tid  = threadIdx.x;
    const int wave = tid >> 6;              // 0..7
    const int lane = tid & 63;
    const int wm   = wave >> 2;             // 0..1 -> rows wm*128..+127
    const int wn   = wave & 3;              // 0..3 -> cols wn*(NF*16)..

    // XCD-aware bijective block swizzle (all launches: nwg % 8 == 0)
    const int nwg  = gridDim.x * gridDim.y;
    const int orig = blockIdx.y * gridDim.x + blockIdx.x;
    const int swz  = (orig & 7) * (nwg >> 3) + (orig >> 3);
    const int m0   = (swz % gridDim.x) << 8;         // gridDim.x = M/256 = 16
    const int n0   = (swz / gridDim.x) * BN;

    const int lrow = lane & 15;
    // swizzled within-row chunk position for ds_read (constant per lane:
    // row = 16k + lrow  ->  (row>>1)&3 == (lrow>>1)&3)
    const int px   = (((lane >> 4) ^ ((lrow >> 1) & 3)) << 3);
    const int aoff = ((wm << 7) + lrow) * 32 + px;
    const int boff = (wn * (NF * 16) + lrow) * 32 + px;
    const unsigned aAb = lds_addr(As) + (unsigned)(aoff * 2);
    const unsigned aBb = lds_addr(Bs) + (unsigned)(boff * 2);

    // staging source (global pre-swizzled so linear global_load_lds dest +
    // swizzled ds_read agree): thread covers LDS row tid>>2, chunk tid&3.
    const int srow = tid >> 2;                       // 0..127 per round
    const int scol = (((tid & 3) ^ ((tid >> 3) & 3)) << 3);
    const u16* Ag = A  + (long)(m0 + srow) * K + scol;
    const u16* Bg = Bw + (long)(n0 + srow) * K + scol;

    f32x4 acc[8][NF] = {};
    bf16x8 bfr[NF];

    const int NT = K >> 5;                 // K-tiles of 32 (>= 64 here)

    // prologue: stage tiles 0,1,2; wait own tile-0 loads; barrier = everyone's
    STAGE_A(0, 0); STAGE_B(0, 0);
    STAGE_A(1, 1); STAGE_B(1, 1);
    STAGE_A(2, 2); STAGE_B(2, 2);
    SCHED0;
    if constexpr (NF == 4) { VM_WAIT(8); } else { VM_WAIT(6); }
    SBAR; SCHED0;

    // main loop: stage t+3, compute t; allow tiles t+2,t+3 (= 2*LPT) in flight
    for (int t = 0; t < NT - 3; ++t) {
        if constexpr (NF == 4) { KTILE(t, 1, VM_WAIT(8)); }
        else                   { KTILE(t, 1, VM_WAIT(6)); }
    }
    // peeled tail: no staging; shrink the allowance so remaining tiles land
    if constexpr (NF == 4) { KTILE((NT - 3), 0, VM_WAIT(4)); }
    else                   { KTILE((NT - 3), 0, VM_WAIT(3)); }
    KTILE((NT - 2), 0, VM_WAIT(0));
    KTILE((NT - 1), 0, ((void)0));

    // ---- epilogue (C/D: col = lane&15, row = (lane>>4)*4 + r) ----
    const int drow = (lane >> 4) << 2;
    if constexpr (EPI == 1) {
#pragma unroll
        for (int mi8 = 0; mi8 < 8; ++mi8) {
            const int rb = m0 + (wm << 7) + ((mi8 >> 2) << 6) + ((mi8 & 3) << 4) + drow;
#pragma unroll
            for (int ni = 0; ni < NF; ++ni) {
                const int col = n0 + wn * (NF * 16) + ni * 16 + lrow;
#pragma unroll
                for (int r = 0; r < 4; ++r)
                    outp[(long)(rb + r) * N + col] = f2bf(acc[mi8][ni][r]);
            }
        }
    } else {
        // paired GELU epilogue: even lanes own tile ni, odd lanes tile ni+1;
        // every lane computes exactly one erf per output value.
        const int No = N >> 1;
#pragma unroll
        for (int mi8 = 0; mi8 < 8; ++mi8) {
            const int rb = m0 + (wm << 7) + ((mi8 >> 2) << 6) + ((mi8 & 3) << 4) + drow;
#pragma unroll
            for (int ni = 0; ni < NF; ni += 2) {
                const int colown = n0 + wn * 64 + (ni + (lane & 1)) * 16 + lrow;
#pragma unroll
                for (int r = 0; r < 4; ++r) {
                    float a = acc[mi8][ni][r];
                    float b = acc[mi8][ni + 1][r];
                    float a1 = __shfl_xor(a, 1);
                    float b1 = __shfl_xor(b, 1);
                    float g = (lane & 1) ? b1 : a;
                    float u = (lane & 1) ? b  : a1;
                    float act = 0.5f * g * (1.f + fast_erf(g * 0.70710678f)) * u;
                    outp[(long)(rb + r) * No + (colown >> 1)] = f2bf(act);
                }
            }
        }
    }
}

// ---------------------------------------------------------------------------
// RoPE + repack qkv(bf16 [M][4096]) -> Qh [B][NH][S][HD], Kh [B][NKV][S][HD]
// ---------------------------------------------------------------------------
__global__ __launch_bounds__(128) void rope_repack_k(const u16* __restrict__ qkv,
                                                     u16* __restrict__ Qh,
                                                     u16* __restrict__ Kh) {
    const int m = blockIdx.x;       // token 0..4095
    const int slot = blockIdx.y;    // 0..15 q head, 16..23 kv head
    const int d = threadIdx.x;      // 0..127
    const int b = m >> 11, s = m & 2047;
    const int colbase = (slot < 16) ? (slot << 7) : (2048 + ((slot - 16) << 7));
    const float xv = bf2f(qkv[(long)m * 4096 + colbase + d]);
    const float xp = bf2f(qkv[(long)m * 4096 + colbase + (d ^ 64)]);
    const int i = d & 63;
    // 10000^(-2i/128) = exp2(-i * log2(10000)/64)
    const float inv = exp2f(-(float)i * 0.20762050593045864f);
    const float fr = (float)s * inv;
    const float cs = cosf(fr), sn = sinf(fr);
    const float ov = (d < 64) ? (xv * cs - xp * sn) : (xv * cs + xp * sn);
    if (slot < 16) {
        Qh[(((long)(b * NH + slot)) * SEQ + s) * HD + d] = f2bf(ov);
    } else {
        Kh[(((long)(b * NKV + (slot - 16))) * SEQ + s) * HD + d] = f2bf(ov);
    }
}

// V transpose: qkv[m][3072+g*128+d] -> Vt [B][NKV][HD][S]
__global__ __launch_bounds__(256) void v_transpose_k(const u16* __restrict__ qkv,
                                                     u16* __restrict__ Vt) {
    __shared__ alignas(16) u16 tile[64][130];
    const int st = blockIdx.x, g = blockIdx.y, b = blockIdx.z;
    const int s0 = st * 64;
    const int tid = threadIdx.x;
#pragma unroll
    for (int i = 0; i < 32; ++i) {
        int idx = i * 256 + tid;
        int sl = idx >> 7, d = idx & 127;
        tile[sl][d] = qkv[(long)(b * SEQ + s0 + sl) * 4096 + 3072 + g * 128 + d];
    }
    __syncthreads();
#pragma unroll
    for (int i = 0; i < 32; ++i) {
        int idx = i * 256 + tid;
        int d = idx >> 6, sl = idx & 63;
        Vt[((long)(b * NKV + g) * HD + d) * SEQ + s0 + sl] = tile[sl][d];
    }
}

// ---------------------------------------------------------------------------
// Flash attention. 4 waves/block, Q-tile 64 (wave owns 16 q rows), K-tile 64.
// ---------------------------------------------------------------------------
__global__ __launch_bounds__(256) void flash_attn_k(const u16* __restrict__ Qh,
                                                    const u16* __restrict__ Kh,
                                                    const u16* __restrict__ Vt,
                                                    u16* __restrict__ attn) {
    __shared__ alignas(16) u16 Qs[64 * 128];
    __shared__ alignas(16) u16 Ks[64 * 128];
    __shared__ alignas(16) u16 Vts[128 * 64];
    __shared__ alignas(16) u16 Ps[4][16 * 64];
    const int tid = threadIdx.x;
    const int wave = tid >> 6, lane = tid & 63;
    const int qt = blockIdx.x, h = blockIdx.y, b = blockIdx.z;
    const int g = h >> 1;                    // GQA group of 2
    const int q0 = qt * 64;
    const u16* Qg = Qh + (((long)(b * NH + h) * SEQ) + q0) * HD;
    const u16* Kg = Kh + ((long)(b * NKV + g) * SEQ) * HD;
    const u16* Vg = Vt + ((long)(b * NKV + g) * HD) * SEQ;

    {   // stage Q tile (contiguous 16KB)
        const int4* src = (const int4*)Qg;
        int4* dst = (int4*)Qs;
#pragma unroll
        for (int i = 0; i < 4; ++i) dst[tid + i * 256] = src[tid + i * 256];
    }
    __syncthreads();
    const int lrow = lane & 15;
    const int kq = (lane >> 4) << 3;
    bf16x8 aq[4];
#pragma unroll
    for (int ks = 0; ks < 4; ++ks)
        aq[ks] = *(const bf16x8*)(Qs + (wave * 16 + lrow) * 128 + ks * 32 + kq);

    f32x4 o[8] = {};
    float mrow[4], lsum[4];
#pragma unroll
    for (int r = 0; r < 4; ++r) { mrow[r] = -1e30f; lsum[r] = 0.f; }

    const int jlo = (q0 - (WIN - 1)) > 0 ? (q0 - (WIN - 1)) : 0;
    const int t0 = jlo >> 6, t1 = q0 >> 6;
    for (int jt = t0; jt <= t1; ++jt) {
        const int j0 = jt * 64;
        __syncthreads();   // prior tile's LDS reads done
        {   // stage K tile
            const int4* src = (const int4*)(Kg + (long)j0 * HD);
            int4* dst = (int4*)Ks;
#pragma unroll
            for (int i = 0; i < 4; ++i) dst[tid + i * 256] = src[tid + i * 256];
        }
        {   // stage Vt tile: 128 rows x 64 cols
            const int row = tid >> 1, half = tid & 1;
            const int4* src = (const int4*)(Vg + (long)row * SEQ + j0 + half * 32);
            int4* dst = (int4*)(Vts + row * 64 + half * 32);
#pragma unroll
            for (int i = 0; i < 4; ++i) dst[i] = src[i];
        }
        __syncthreads();

        // ---- scores: 16x64 per wave
        f32x4 sc[4];
#pragma unroll
        for (int nt = 0; nt < 4; ++nt) {
            f32x4 s = {};
#pragma unroll
            for (int ks = 0; ks < 4; ++ks) {
                bf16x8 bk = *(const bf16x8*)(Ks + (nt * 16 + lrow) * 128 + ks * 32 + kq);
                s = __builtin_amdgcn_mfma_f32_16x16x32_bf16(aq[ks], bk, s, 0, 0, 0);
            }
            sc[nt] = s;
        }

        // ---- mask + online softmax
        const int qbase = q0 + wave * 16 + ((lane >> 4) << 2);
        float pv[4][4];   // [nt][r]
#pragma unroll
        for (int r = 0; r < 4; ++r) {
            const int qi = qbase + r;
            float mx = -1e30f;
#pragma unroll
            for (int nt = 0; nt < 4; ++nt) {
                const int ki = j0 + nt * 16 + lrow;
                float s = sc[nt][r] * 0.08838834764831845f;  // 1/sqrt(128)
                bool valid = (ki <= qi) && (qi - ki < WIN);
                s = valid ? s : -1e30f;
                sc[nt][r] = s;
                mx = fmaxf(mx, s);
            }
            mx = fmaxf(mx, __shfl_xor(mx, 1));
            mx = fmaxf(mx, __shfl_xor(mx, 2));
            mx = fmaxf(mx, __shfl_xor(mx, 4));
            mx = fmaxf(mx, __shfl_xor(mx, 8));
            const float mn = fmaxf(mrow[r], mx);
            const float alpha = __expf(mrow[r] - mn);
            float rsum = 0.f;
#pragma unroll
            for (int nt = 0; nt < 4; ++nt) {
                float s = sc[nt][r];
                float p = (s > -1e29f) ? __expf(s - mn) : 0.f;
                pv[nt][r] = p;
                rsum += p;
            }
            rsum += __shfl_xor(rsum, 1);
            rsum += __shfl_xor(rsum, 2);
            rsum += __shfl_xor(rsum, 4);
            rsum += __shfl_xor(rsum, 8);
            lsum[r] = lsum[r] * alpha + rsum;
            mrow[r] = mn;
#pragma unroll
            for (int dt = 0; dt < 8; ++dt) o[dt][r] *= alpha;
        }

        // ---- P: C-layout -> LDS (per-wave region, A-layout for PV)
        u16* myP = (u16*)Ps[wave];
#pragma unroll
        for (int r = 0; r < 4; ++r) {
            const int prow = ((lane >> 4) << 2) + r;
#pragma unroll
            for (int nt = 0; nt < 4; ++nt)
                myP[prow * 64 + nt * 16 + lrow] = f2bf(pv[nt][r]);
        }
        __syncthreads();

        // ---- PV: O[16][128] += P[16][64] @ V[64][128]
#pragma unroll
        for (int kst = 0; kst < 2; ++kst) {
            bf16x8 ap = *(const bf16x8*)(myP + lrow * 64 + kst * 32 + kq);
#pragma unroll
            for (int dt = 0; dt < 8; ++dt) {
                bf16x8 bv = *(const bf16x8*)(Vts + (dt * 16 + lrow) * 64 + kst * 32 + kq);
                o[dt] = __builtin_amdgcn_mfma_f32_16x16x32_bf16(ap, bv, o[dt], 0, 0, 0);
            }
        }
    }

    // ---- epilogue
#pragma unroll
    for (int r = 0; r < 4; ++r) {
        const int qi = q0 + wave * 16 + ((lane >> 4) << 2) + r;
        const float inv = 1.f / lsum[r];
        const long mrowg = (long)b * SEQ + qi;
#pragma unroll
        for (int dt = 0; dt < 8; ++dt)
            attn[mrowg * (NH * HD) + h * 128 + dt * 16 + lrow] = f2bf(o[dt][r] * inv);
    }
}

// ---------------------------------------------------------------------------
// h2 = x + rmsnorm(attn_out)*w_post (bf16) ; ffin = bf16(rmsnorm(h2)*w_pre)
// ---------------------------------------------------------------------------
__global__ __launch_bounds__(256) void addnorm2_k(const float* __restrict__ x,
                                                  const u16* __restrict__ ao,
                                                  const float* __restrict__ wpost,
                                                  const float* __restrict__ wpre,
                                                  u16* __restrict__ h2,
                                                  u16* __restrict__ ffin) {
    const int row = blockIdx.x, t = threadIdx.x;
    __shared__ float sb[4];
    const long base = (long)row * HSZ;
    ushort4 a4_0 = ((const ushort4*)(ao + base))[t];
    ushort4 a4_1 = ((const ushort4*)(ao + base))[t + 256];
    float4 a0, a1;
    a0.x = bf2f(a4_0.x); a0.y = bf2f(a4_0.y); a0.z = bf2f(a4_0.z); a0.w = bf2f(a4_0.w);
    a1.x = bf2f(a4_1.x); a1.y = bf2f(a4_1.y); a1.z = bf2f(a4_1.z); a1.w = bf2f(a4_1.w);
    float ss = sq4(a0) + sq4(a1);
#pragma unroll
    for (int o = 32; o; o >>= 1) ss += __shfl_xor(ss, o);
    if ((t & 63) == 0) sb[t >> 6] = ss;
    __syncthreads();
    ss = sb[0] + sb[1] + sb[2] + sb[3];
    const float rs1 = rsqrtf(ss * (1.f / HSZ) + 1e-6f);

    const float4* xr = (const float4*)(x + base);
    float4 x0 = xr[t], x1 = xr[t + 256];
    float4 wp0 = ((const float4*)wpost)[t], wp1 = ((const float4*)wpost)[t + 256];
    float4 h0, h1;
    h0.x = x0.x + a0.x * rs1 * wp0.x; h0.y = x0.y + a0.y * rs1 * wp0.y;
    h0.z = x0.z + a0.z * rs1 * wp0.z; h0.w = x0.w + a0.w * rs1 * wp0.w;
    h1.x = x1.x + a1.x * rs1 * wp1.x; h1.y = x1.y + a1.y * rs1 * wp1.y;
    h1.z = x1.z + a1.z * rs1 * wp1.z; h1.w = x1.w + a1.w * rs1 * wp1.w;
    ushort4 hb0, hb1;
    hb0.x = f2bf(h0.x); hb0.y = f2bf(h0.y); hb0.z = f2bf(h0.z); hb0.w = f2bf(h0.w);
    hb1.x = f2bf(h1.x); hb1.y = f2bf(h1.y); hb1.z = f2bf(h1.z); hb1.w = f2bf(h1.w);
    ((ushort4*)(h2 + base))[t] = hb0;
    ((ushort4*)(h2 + base))[t + 256] = hb1;

    float ss2 = sq4(h0) + sq4(h1);
#pragma unroll
    for (int o = 32; o; o >>= 1) ss2 += __shfl_xor(ss2, o);
    __syncthreads();   // all sb reads above done
    if ((t & 63) == 0) sb[t >> 6] = ss2;
    __syncthreads();
    ss2 = sb[0] + sb[1] + sb[2] + sb[3];
    const float rs2 = rsqrtf(ss2 * (1.f / HSZ) + 1e-6f);
    float4 wq0 = ((const float4*)wpre)[t], wq1 = ((const float4*)wpre)[t + 256];
    ushort4 o0, o1;
    o0.x = f2bf(h0.x * rs2 * wq0.x); o0.y = f2bf(h0.y * rs2 * wq0.y);
    o0.z = f2bf(h0.z * rs2 * wq0.z); o0.w = f2bf(h0.w * rs2 * wq0.w);
    o1.x = f2bf(h1.x * rs2 * wq1.x); o1.y = f2bf(h1.y * rs2 * wq1.y);
    o1.z = f2bf(h1.z * rs2 * wq1.z); o1.w = f2bf(h1.w * rs2 * wq1.w);
    ushort4* fr = (ushort4*)(ffin + base);
    fr[t] = o0; fr[t + 256] = o1;
}

// out = (h2 + rmsnorm(ffn_out)*w_post_ffn) * layer_scalar   (f32 out)
__global__ __launch_bounds__(256) void final_k(const u16* __restrict__ h2,
                                               const u16* __restrict__ fo,
                                               const float* __restrict__ wpost,
                                               const float* __restrict__ lscal,
                                               float* __restrict__ out) {
    const int row = blockIdx.x, t = threadIdx.x;
    __shared__ float sb[4];
    const long base = (long)row * HSZ;
    ushort4 f4_0 = ((const ushort4*)(fo + base))[t];
    ushort4 f4_1 = ((const ushort4*)(fo + base))[t + 256];
    float4 f0, f1;
    f0.x = bf2f(f4_0.x); f0.y = bf2f(f4_0.y); f0.z = bf2f(f4_0.z); f0.w = bf2f(f4_0.w);
    f1.x = bf2f(f4_1.x); f1.y = bf2f(f4_1.y); f1.z = bf2f(f4_1.z); f1.w = bf2f(f4_1.w);
    float ss = sq4(f0) + sq4(f1);
#pragma unroll
    for (int o = 32; o; o >>= 1) ss += __shfl_xor(ss, o);
    if ((t & 63) == 0) sb[t >> 6] = ss;
    __syncthreads();
    ss = sb[0] + sb[1] + sb[2] + sb[3];
    const float rs = rsqrtf(ss * (1.f / HSZ) + 1e-6f);
    const float sc = lscal[0];
    ushort4 h4_0 = ((const ushort4*)(h2 + base))[t];
    ushort4 h4_1 = ((const ushort4*)(h2 + base))[t + 256];
    float4 wp0 = ((const float4*)wpost)[t], wp1 = ((const float4*)wpost)[t + 256];
    float4 r0, r1;
    r0.x = (bf2f(h4_0.x) + f0.x * rs * wp0.x) * sc;
    r0.y = (bf2f(h4_0.y) + f0.y * rs * wp0.y) * sc;
    r0.z = (bf2f(h4_0.z) + f0.z * rs * wp0.z) * sc;
    r0.w = (bf2f(h4_0.w) + f0.w * rs * wp0.w) * sc;
    r1.x = (bf2f(h4_1.x) + f1.x * rs * wp1.x) * sc;
    r1.y = (bf2f(h4_1.y) + f1.y * rs * wp1.y) * sc;
    r1.z = (bf2f(h4_1.z) + f1.z * rs * wp1.z) * sc;
    r1.w = (bf2f(h4_1.w) + f1.w * rs * wp1.w) * sc;
    ((float4*)(out + base))[t] = r0;
    ((float4*)(out + base))[t + 256] = r1;
}

// ---------------------------------------------------------------------------
extern "C" void kernel_launch(void* const* d_in, const int* in_sizes, int n_in,
                              void* d_out, int out_size, void* d_ws, size_t ws_size,
                              hipStream_t stream) {
    (void)in_sizes; (void)n_in; (void)out_size;
    const float* x     = (const float*)d_in[0];
    const float* wq    = (const float*)d_in[1];
    const float* wk    = (const float*)d_in[2];
    const float* wv    = (const float*)d_in[3];
    const float* wo    = (const float*)d_in[4];
    const float* w_in  = (const float*)d_in[5];
    const float* w_pa  = (const float*)d_in[6];
    const float* w_pf  = (const float*)d_in[7];
    const float* w_pff = (const float*)d_in[8];
    const float* wgate = (const float*)d_in[9];
    const float* wup   = (const float*)d_in[10];
    const float* wdown = (const float*)d_in[11];
    const float* lscal = (const float*)d_in[12];
    float* out = (float*)d_out;

    // -------- workspace layout: 264 MiB total, phase-overlapped ----------
    const size_t NEED = 276824064ull;  // 264 MiB
    if (ws_size < NEED) return;
    char* ws = (char*)d_ws;
    u16* Wqkv  = (u16*)(ws);                             // 16 MB  [whole run]
    u16* Wo    = (u16*)(ws + 16777216);                  //  8 MB
    u16* Wgu   = (u16*)(ws + 25165824);                  // 64 MB
    u16* Wdown = (u16*)(ws + 92274688);                  // 32 MB
    u16* act   = (u16*)(ws + 125829120);                 // 64 MB  [gate-up out]
    u16* R1    = (u16*)(ws + 192937984);                 // 32 MB
    u16* R2    = (u16*)(ws + 226492416);                 // 32 MB
    u16* R3    = (u16*)(ws + 260046848);                 // 16 MB
    u16* qkvb = R1;
    u16* aout = R1;
    u16* ffin = R1 + 8388608;
    u16* fout = R1 + 8388608;
    u16* Qh = R2;
    u16* Kh = R2 + 8388608;
    u16* Vt = R2 + 12582912;
    u16* h2 = R2;
    u16* hnorm = R3;
    u16* attn  = R3;

    // weight conversions (re-run every launch; ws is re-poisoned)
    cvt_f32_bf16_k<<<4096, 256, 0, stream>>>(wq, Wqkv, 2048 * 2048 / 4);
    cvt_f32_bf16_k<<<2048, 256, 0, stream>>>(wk, Wqkv + 2048 * 2048, 1024 * 2048 / 4);
    cvt_f32_bf16_k<<<2048, 256, 0, stream>>>(wv, Wqkv + 3072 * 2048, 1024 * 2048 / 4);
    cvt_f32_bf16_k<<<4096, 256, 0, stream>>>(wo, Wo, 2048 * 2048 / 4);
    cvt_gu_k<<<32768, 256, 0, stream>>>(wgate, wup, Wgu);
    cvt_f32_bf16_k<<<16384, 256, 0, stream>>>(wdown, Wdown, HSZ * INTER / 4);

    // block pipeline. GEMM grids: dim3(M/256, N/BN); all have nwg % 8 == 0.
    rmsnorm_bf16_k<<<MTOK, 256, 0, stream>>>(x, w_in, hnorm);
    gemm_pipe<4, 1><<<dim3(16, 16), 512, 0, stream>>>(hnorm, Wqkv, qkvb, 4096, HSZ);
    rope_repack_k<<<dim3(MTOK, 24), 128, 0, stream>>>(qkvb, Qh, Kh);
    v_transpose_k<<<dim3(SEQ / 64, NKV, BATCH), 256, 0, stream>>>(qkvb, Vt);
    flash_attn_k<<<dim3(SEQ / 64, NH, BATCH), 256, 0, stream>>>(Qh, Kh, Vt, attn);
    gemm_pipe<2, 1><<<dim3(16, 16), 512, 0, stream>>>(attn, Wo, aout, HSZ, HSZ);
    addnorm2_k<<<MTOK, 256, 0, stream>>>(x, aout, w_pa, w_pf, h2, ffin);
    gemm_pipe<4, 2><<<dim3(16, 64), 512, 0, stream>>>(ffin, Wgu, act, 2 * INTER, HSZ);
    gemm_pipe<2, 1><<<dim3(16, 16), 512, 0, stream>>>(act, Wdown, fout, HSZ, INTER);
    final_k<<<MTOK, 256, 0, stream>>>(h2, fout, w_pff, lscal, out);
}